// Round 10
// baseline (199.572 us; speedup 1.0000x reference)
//
#include <hip/hip_runtime.h>

#define NUM_FIELDS 32
#define EMBED_DIM  64
#define NUM_PAIRS  496   // 32*31/2
#define P4         (NUM_PAIRS / 4)   // 124 float4 outputs per row
#define WAVES      8     // one batch row per wave; block = 512 threads

// Native vector type: __builtin_nontemporal_* requires scalar/vector-of-scalar
// pointee, not HIP_vector_type (a struct).
typedef float f4 __attribute__((ext_vector_type(4)));

// Compile-time pair index table, identical order to the Python reference:
// [(i,j) for i in range(F-1) for j in range(i+1, F)]
// Packed 4 indices per uint word: the epilogue loads ONE dword for 4 row
// indices and ONE dword for 4 col indices.
struct PairsPacked {
    unsigned int r4[P4];
    unsigned int c4[P4];
};
constexpr PairsPacked make_pairs() {
    unsigned char r[NUM_PAIRS] = {};
    unsigned char c[NUM_PAIRS] = {};
    int p = 0;
    for (int i = 0; i < NUM_FIELDS - 1; ++i)
        for (int j = i + 1; j < NUM_FIELDS; ++j) {
            r[p] = (unsigned char)i;
            c[p] = (unsigned char)j;
            ++p;
        }
    PairsPacked t{};
    for (int q = 0; q < P4; ++q) {
        t.r4[q] = (unsigned)r[4 * q + 0]        | ((unsigned)r[4 * q + 1] << 8)
                | ((unsigned)r[4 * q + 2] << 16) | ((unsigned)r[4 * q + 3] << 24);
        t.c4[q] = (unsigned)c[4 * q + 0]        | ((unsigned)c[4 * q + 1] << 8)
                | ((unsigned)c[4 * q + 2] << 16) | ((unsigned)c[4 * q + 3] << 24);
    }
    return t;
}
__device__ constexpr PairsPacked PAIRS = make_pairs();

// One batch row per WAVE (wave-decoupled: no __syncthreads anywhere).
//  Loads:  row = 512 f4s; lane loads f4[k*64+lane], k=0..7 — each instruction
//          covers a contiguous 1 KiB span (perfect coalescing). PLAIN loads
//          (not nontemporal): x is 134 MB < 256 MB Infinity Cache and is
//          re-read every bench iteration — allow L3 residency. R4 A/B test:
//          nt-loads guaranteed HBM reads; plain loads give L3 a chance.
//  Reduce: hsum each f4, then one 16-lane shfl_xor butterfly over all 8
//          partials. After it, every lane in group g (=lane/16) holds
//          s[4k+g] for k=0..7. Lane (lane%16)==0 of each group writes its 8
//          sums to the wave-private LDS slice (static p[k] indices, distinct
//          banks 4k+g).
//  Epilogue: same wave reads the 32 sums back (lgkmcnt dependency only — no
//          barrier needed within a wave). LDS reads are conflict-free: the
//          32-float slice spans exactly 32 banks, so distinct indices hit
//          distinct banks and equal indices broadcast. Output stores stay
//          NONTEMPORAL: out is write-once, never re-read — don't let it
//          steal L3 capacity from x.
__global__ __launch_bounds__(WAVES * 64)
void opn_kernel(const float* __restrict__ x, float* __restrict__ out, int batch) {
    const int wave = threadIdx.x >> 6;   // 0..7
    const int lane = threadIdx.x & 63;
    const int row  = blockIdx.x * WAVES + wave;
    if (row >= batch) return;

    __shared__ float s_sh[WAVES][NUM_FIELDS];

    const f4* __restrict__ x4 =
        (const f4*)(x + (size_t)row * NUM_FIELDS * EMBED_DIM);

    // All 8 loads issued up front (independent -> 8 outstanding per lane).
    f4 v[8];
    #pragma unroll
    for (int k = 0; k < 8; ++k)
        v[k] = x4[k * 64 + lane];        // plain load — L3-cacheable

    float p[8];
    #pragma unroll
    for (int k = 0; k < 8; ++k)
        p[k] = (v[k].x + v[k].y) + (v[k].z + v[k].w);

    // 16-lane butterfly (xor masks < 16 stay inside the group of 16).
    #pragma unroll
    for (int off = 8; off >= 1; off >>= 1) {
        #pragma unroll
        for (int k = 0; k < 8; ++k)
            p[k] += __shfl_xor(p[k], off);
    }

    const int g = lane >> 4;             // group 0..3
    if ((lane & 15) == 0) {
        #pragma unroll
        for (int k = 0; k < 8; ++k)      // static register indices
            s_sh[wave][4 * k + g] = p[k];
    }
    // Same-wave LDS write->read: compiler-inserted s_waitcnt lgkmcnt(0)
    // provides ordering; no __syncthreads required (wave-private slice).

    f4* __restrict__ o4 = (f4*)(out + (size_t)row * NUM_PAIRS);
    #pragma unroll
    for (int rep = 0; rep < 2; ++rep) {
        const int i = rep * 64 + lane;
        if (i < P4) {
            const unsigned rr = PAIRS.r4[i];   // 4 row indices, one dword
            const unsigned cc = PAIRS.c4[i];   // 4 col indices, one dword
            f4 r;
            r.x = s_sh[wave][rr & 255]         * s_sh[wave][cc & 255];
            r.y = s_sh[wave][(rr >> 8) & 255]  * s_sh[wave][(cc >> 8) & 255];
            r.z = s_sh[wave][(rr >> 16) & 255] * s_sh[wave][(cc >> 16) & 255];
            r.w = s_sh[wave][rr >> 24]         * s_sh[wave][cc >> 24];
            __builtin_nontemporal_store(r, &o4[i]);
        }
    }
}

extern "C" void kernel_launch(void* const* d_in, const int* in_sizes, int n_in,
                              void* d_out, int out_size, void* d_ws, size_t ws_size,
                              hipStream_t stream) {
    const float* x = (const float*)d_in[0];
    float* out = (float*)d_out;
    const int batch = in_sizes[0] / (NUM_FIELDS * EMBED_DIM);  // 16384
    const int grid = (batch + WAVES - 1) / WAVES;              // 2048
    opn_kernel<<<grid, WAVES * 64, 0, stream>>>(x, out, batch);
}

// Round 12
// 187.501 us; speedup vs baseline: 1.0644x; 1.0644x over previous
//
#include <hip/hip_runtime.h>

#define NUM_FIELDS 32
#define EMBED_DIM  64
#define NUM_PAIRS  496   // 32*31/2
#define P4         (NUM_PAIRS / 4)   // 124 float4 outputs per row
#define WAVES      8     // one batch row per wave; block = 512 threads

// Native vector type: __builtin_nontemporal_* requires scalar/vector-of-scalar
// pointee, not HIP_vector_type (a struct).
typedef float f4 __attribute__((ext_vector_type(4)));

// Compile-time pair index table, identical order to the Python reference:
// [(i,j) for i in range(F-1) for j in range(i+1, F)]
// Packed 4 indices per uint word: the epilogue loads ONE dword for 4 row
// indices and ONE dword for 4 col indices.
struct PairsPacked {
    unsigned int r4[P4];
    unsigned int c4[P4];
};
constexpr PairsPacked make_pairs() {
    unsigned char r[NUM_PAIRS] = {};
    unsigned char c[NUM_PAIRS] = {};
    int p = 0;
    for (int i = 0; i < NUM_FIELDS - 1; ++i)
        for (int j = i + 1; j < NUM_FIELDS; ++j) {
            r[p] = (unsigned char)i;
            c[p] = (unsigned char)j;
            ++p;
        }
    PairsPacked t{};
    for (int q = 0; q < P4; ++q) {
        t.r4[q] = (unsigned)r[4 * q + 0]        | ((unsigned)r[4 * q + 1] << 8)
                | ((unsigned)r[4 * q + 2] << 16) | ((unsigned)r[4 * q + 3] << 24);
        t.c4[q] = (unsigned)c[4 * q + 0]        | ((unsigned)c[4 * q + 1] << 8)
                | ((unsigned)c[4 * q + 2] << 16) | ((unsigned)c[4 * q + 3] << 24);
    }
    return t;
}
__device__ constexpr PairsPacked PAIRS = make_pairs();

// One batch row per WAVE (wave-decoupled: no __syncthreads anywhere).
//  Loads:  row = 512 f4s; lane loads f4[k*64+lane], k=0..7 — each instruction
//          covers a contiguous 1 KiB span (perfect coalescing).
//          NONTEMPORAL loads: measured A/B (R4 vs R10): nt=188.07 µs total,
//          plain=199.57 µs. x is streamed once/iter with no retained reuse
//          (harness fills flush L3 between iters); plain loads only add
//          L2/L3 allocation churn against the write stream. nt wins by ~12 µs.
//  Reduce: hsum each f4, then one 16-lane shfl_xor butterfly over all 8
//          partials. After it, every lane in group g (=lane/16) holds
//          s[4k+g] for k=0..7. Lane (lane%16)==0 of each group writes its 8
//          sums to the wave-private LDS slice (static p[k] indices, distinct
//          banks 4k+g).
//  Epilogue: same wave reads the 32 sums back (lgkmcnt dependency only — no
//          barrier needed within a wave). LDS reads are conflict-free: the
//          32-float slice spans exactly 32 banks, so distinct indices hit
//          distinct banks and equal indices broadcast. Output stores are
//          NONTEMPORAL: out is write-once, never re-read.
__global__ __launch_bounds__(WAVES * 64)
void opn_kernel(const float* __restrict__ x, float* __restrict__ out, int batch) {
    const int wave = threadIdx.x >> 6;   // 0..7
    const int lane = threadIdx.x & 63;
    const int row  = blockIdx.x * WAVES + wave;
    if (row >= batch) return;

    __shared__ float s_sh[WAVES][NUM_FIELDS];

    const f4* __restrict__ x4 =
        (const f4*)(x + (size_t)row * NUM_FIELDS * EMBED_DIM);

    // All 8 loads issued up front (independent -> 8 outstanding per lane).
    f4 v[8];
    #pragma unroll
    for (int k = 0; k < 8; ++k)
        v[k] = __builtin_nontemporal_load(&x4[k * 64 + lane]);

    float p[8];
    #pragma unroll
    for (int k = 0; k < 8; ++k)
        p[k] = (v[k].x + v[k].y) + (v[k].z + v[k].w);

    // 16-lane butterfly (xor masks < 16 stay inside the group of 16).
    #pragma unroll
    for (int off = 8; off >= 1; off >>= 1) {
        #pragma unroll
        for (int k = 0; k < 8; ++k)
            p[k] += __shfl_xor(p[k], off);
    }

    const int g = lane >> 4;             // group 0..3
    if ((lane & 15) == 0) {
        #pragma unroll
        for (int k = 0; k < 8; ++k)      // static register indices
            s_sh[wave][4 * k + g] = p[k];
    }
    // Same-wave LDS write->read: compiler-inserted s_waitcnt lgkmcnt(0)
    // provides ordering; no __syncthreads required (wave-private slice).

    f4* __restrict__ o4 = (f4*)(out + (size_t)row * NUM_PAIRS);
    #pragma unroll
    for (int rep = 0; rep < 2; ++rep) {
        const int i = rep * 64 + lane;
        if (i < P4) {
            const unsigned rr = PAIRS.r4[i];   // 4 row indices, one dword
            const unsigned cc = PAIRS.c4[i];   // 4 col indices, one dword
            f4 r;
            r.x = s_sh[wave][rr & 255]         * s_sh[wave][cc & 255];
            r.y = s_sh[wave][(rr >> 8) & 255]  * s_sh[wave][(cc >> 8) & 255];
            r.z = s_sh[wave][(rr >> 16) & 255] * s_sh[wave][(cc >> 16) & 255];
            r.w = s_sh[wave][rr >> 24]         * s_sh[wave][cc >> 24];
            __builtin_nontemporal_store(r, &o4[i]);
        }
    }
}

extern "C" void kernel_launch(void* const* d_in, const int* in_sizes, int n_in,
                              void* d_out, int out_size, void* d_ws, size_t ws_size,
                              hipStream_t stream) {
    const float* x = (const float*)d_in[0];
    float* out = (float*)d_out;
    const int batch = in_sizes[0] / (NUM_FIELDS * EMBED_DIM);  // 16384
    const int grid = (batch + WAVES - 1) / WAVES;              // 2048
    opn_kernel<<<grid, WAVES * 64, 0, stream>>>(x, out, batch);
}